// Round 1
// baseline (442.235 us; speedup 1.0000x reference)
//
#include <hip/hip_runtime.h>
#include <hip/hip_bf16.h>

#define TPB 256
#define RQ 2   // query points per thread (held in registers)
#define UQ 4   // db points per inner iteration

// Pack [npts,3] fp32 coords into float4 (x, y, z, 0.5*||p||^2)
__global__ __launch_bounds__(TPB) void pack_kernel(const float* __restrict__ src,
                                                   float4* __restrict__ dst, int npts) {
    int i = blockIdx.x * blockDim.x + threadIdx.x;
    if (i < npts) {
        float x = src[3 * i + 0];
        float y = src[3 * i + 1];
        float z = src[3 * i + 2];
        dst[i] = make_float4(x, y, z, 0.5f * (x * x + y * y + z * z));
    }
}

// One direction per blockIdx.z: z=0 queries pack1 against pack2, z=1 the reverse.
// d(n,m) = sq1[n] + sq2[m] - 2 p.q = 2*ph[n] + 2*(h2[m] - p.q)
// dist(n) = 2*(ph[n] + min_m (h2[m] - p.q))
__global__ __launch_bounds__(TPB) void chamfer_main(const float4* __restrict__ pack1,
                                                    const float4* __restrict__ pack2,
                                                    float* __restrict__ out,
                                                    int N, int M) {
    const int b = blockIdx.y;
    const int dir = blockIdx.z;
    const float4* __restrict__ P = dir ? (pack2 + (size_t)b * M) : (pack1 + (size_t)b * N);
    const float4* __restrict__ Q = dir ? (pack1 + (size_t)b * N) : (pack2 + (size_t)b * M);
    const int nq = dir ? M : N;   // number of query points
    const int md = dir ? N : M;   // number of db points

    float px[RQ], py[RQ], pz[RQ], ph[RQ], mn[RQ], valid[RQ];
    const int base = blockIdx.x * (TPB * RQ) + (int)threadIdx.x;
#pragma unroll
    for (int r = 0; r < RQ; ++r) {
        int idx = base + r * TPB;
        int cidx = idx < nq ? idx : (nq - 1);
        float4 p = P[cidx];
        px[r] = -p.x; py[r] = -p.y; pz[r] = -p.z;
        ph[r] = p.w;
        mn[r] = 3.0e38f;
        valid[r] = (idx < nq) ? 1.0f : 0.0f;
    }

#define STEP(qq)                                          \
    {                                                     \
        _Pragma("unroll")                                 \
        for (int r = 0; r < RQ; ++r) {                    \
            float t = fmaf(px[r], (qq).x, (qq).w);        \
            t = fmaf(py[r], (qq).y, t);                   \
            t = fmaf(pz[r], (qq).z, t);                   \
            mn[r] = fminf(mn[r], t);                      \
        }                                                 \
    }

    int m = 0;
    if (md >= 2 * UQ) {
        float4 q0 = Q[0], q1 = Q[1], q2 = Q[2], q3 = Q[3];
        for (; m + 2 * UQ <= md; m += UQ) {
            float4 n0 = Q[m + 4], n1 = Q[m + 5], n2 = Q[m + 6], n3 = Q[m + 7];
            STEP(q0); STEP(q1); STEP(q2); STEP(q3);
            q0 = n0; q1 = n1; q2 = n2; q3 = n3;
        }
        STEP(q0); STEP(q1); STEP(q2); STEP(q3);
        m += UQ;
    }
    for (; m < md; ++m) {
        float4 qq = Q[m];
        STEP(qq);
    }
#undef STEP

    float s = 0.0f;
#pragma unroll
    for (int r = 0; r < RQ; ++r) s += valid[r] * (mn[r] + ph[r]);

    // wave-64 shuffle reduction
#pragma unroll
    for (int off = 32; off > 0; off >>= 1) s += __shfl_down(s, off, 64);
    if ((threadIdx.x & 63) == 0) {
        atomicAdd(out + b, s * (2.0f / (float)nq));
    }
}

// Fallback (no workspace): direct squared distance, 7 ops/pair.
__global__ __launch_bounds__(TPB) void chamfer_raw(const float* __restrict__ xyz1,
                                                   const float* __restrict__ xyz2,
                                                   float* __restrict__ out,
                                                   int N, int M) {
    const int b = blockIdx.y;
    const int dir = blockIdx.z;
    const float* __restrict__ P = dir ? (xyz2 + (size_t)b * M * 3) : (xyz1 + (size_t)b * N * 3);
    const float* __restrict__ Q = dir ? (xyz1 + (size_t)b * N * 3) : (xyz2 + (size_t)b * M * 3);
    const int nq = dir ? M : N;
    const int md = dir ? N : M;

    float px[RQ], py[RQ], pz[RQ], mn[RQ], valid[RQ];
    const int base = blockIdx.x * (TPB * RQ) + (int)threadIdx.x;
#pragma unroll
    for (int r = 0; r < RQ; ++r) {
        int idx = base + r * TPB;
        int cidx = idx < nq ? idx : (nq - 1);
        px[r] = P[3 * cidx + 0];
        py[r] = P[3 * cidx + 1];
        pz[r] = P[3 * cidx + 2];
        mn[r] = 3.0e38f;
        valid[r] = (idx < nq) ? 1.0f : 0.0f;
    }
    for (int m = 0; m < md; ++m) {
        float qx = Q[3 * m + 0], qy = Q[3 * m + 1], qz = Q[3 * m + 2];
#pragma unroll
        for (int r = 0; r < RQ; ++r) {
            float dx = qx - px[r], dy = qy - py[r], dz = qz - pz[r];
            float d = fmaf(dx, dx, fmaf(dy, dy, dz * dz));
            mn[r] = fminf(mn[r], d);
        }
    }
    float s = 0.0f;
#pragma unroll
    for (int r = 0; r < RQ; ++r) s += valid[r] * mn[r];
#pragma unroll
    for (int off = 32; off > 0; off >>= 1) s += __shfl_down(s, off, 64);
    if ((threadIdx.x & 63) == 0) atomicAdd(out + b, s / (float)nq);
}

extern "C" void kernel_launch(void* const* d_in, const int* in_sizes, int n_in,
                              void* d_out, int out_size, void* d_ws, size_t ws_size,
                              hipStream_t stream) {
    const float* xyz1 = (const float*)d_in[0];
    const float* xyz2 = (const float*)d_in[1];
    float* out = (float*)d_out;

    const int B = out_size;                 // one scalar per batch
    const int N = in_sizes[0] / (3 * B);
    const int M = in_sizes[1] / (3 * B);

    hipMemsetAsync(d_out, 0, (size_t)B * sizeof(float), stream);

    const int tot1 = B * N, tot2 = B * M;
    const size_t need = ((size_t)tot1 + (size_t)tot2) * sizeof(float4);
    const int qmax = N > M ? N : M;
    dim3 grid((qmax + TPB * RQ - 1) / (TPB * RQ), B, 2);

    if (ws_size >= need) {
        float4* pack1 = (float4*)d_ws;
        float4* pack2 = pack1 + (size_t)tot1;
        pack_kernel<<<dim3((tot1 + TPB - 1) / TPB), dim3(TPB), 0, stream>>>(xyz1, pack1, tot1);
        pack_kernel<<<dim3((tot2 + TPB - 1) / TPB), dim3(TPB), 0, stream>>>(xyz2, pack2, tot2);
        chamfer_main<<<grid, dim3(TPB), 0, stream>>>(pack1, pack2, out, N, M);
    } else {
        chamfer_raw<<<grid, dim3(TPB), 0, stream>>>(xyz1, xyz2, out, N, M);
    }
}

// Round 2
// 194.089 us; speedup vs baseline: 2.2785x; 2.2785x over previous
//
#include <hip/hip_runtime.h>
#include <hip/hip_bf16.h>

#define TPB 256          // threads per block (4 waves)
#define TS  1024         // db points staged per LDS tile (16 KiB as float4)
#define L   (TS / TPB)   // float4s staged per thread per tile

// One query point per thread. blockIdx.z selects direction:
//   z=0: queries xyz1 against xyz2;  z=1: queries xyz2 against xyz1.
// d(p,q) = ||p||^2 + ||q||^2 - 2 p.q = 2*(ph + (hq - p.q)),  ph=0.5||p||^2, hq=0.5||q||^2
// dist(p) = 2*(ph + min_q (hq - p.q))  -> inner step: 3 fma + 1 min per point.
__global__ __launch_bounds__(TPB) void chamfer_main(const float* __restrict__ xyz1,
                                                    const float* __restrict__ xyz2,
                                                    float* __restrict__ out,
                                                    int N, int M) {
    const int b   = blockIdx.y;
    const int dir = blockIdx.z;
    const float* __restrict__ P = dir ? (xyz2 + (size_t)b * M * 3) : (xyz1 + (size_t)b * N * 3);
    const float* __restrict__ Q = dir ? (xyz1 + (size_t)b * N * 3) : (xyz2 + (size_t)b * M * 3);
    const int nq = dir ? M : N;   // number of query points this direction
    const int md = dir ? N : M;   // number of db points this direction

    // Block-uniform early exit (before any barrier) for fully out-of-range blocks.
    if ((int)blockIdx.x * TPB >= nq) return;

    __shared__ float4 sm[TS];

    const int idx  = blockIdx.x * TPB + (int)threadIdx.x;
    const int cidx = idx < nq ? idx : nq - 1;
    const float qx = P[3 * cidx + 0];
    const float qy = P[3 * cidx + 1];
    const float qz = P[3 * cidx + 2];
    const float px = -qx, py = -qy, pz = -qz;                  // negate once: inner = fma only
    const float ph = 0.5f * (qx * qx + qy * qy + qz * qz);
    const float valid = (idx < nq) ? 1.0f : 0.0f;

    // 4 accumulators to break the serial v_min dependence chain.
    float mn0 = 3.0e38f, mn1 = 3.0e38f, mn2 = 3.0e38f, mn3 = 3.0e38f;

    for (int tile = 0; tile < md; tile += TS) {
        // Cooperative staging: each thread packs L consecutive db points as
        // (x, y, z, 0.5*||.||^2). Tail tiles are padded with duplicates of the
        // last point — duplicates never change a min.
        int p0 = tile + (int)threadIdx.x * L;
#pragma unroll
        for (int k = 0; k < L; ++k) {
            int g = p0 + k;
            g = g < md ? g : md - 1;
            float x = Q[3 * g + 0];
            float y = Q[3 * g + 1];
            float z = Q[3 * g + 2];
            sm[threadIdx.x * L + k] = make_float4(x, y, z, 0.5f * (x * x + y * y + z * z));
        }
        __syncthreads();

        // Inner sweep: wave-uniform LDS reads (broadcast, conflict-free).
        for (int t0 = 0; t0 < TS; t0 += 8) {
#pragma unroll
            for (int j = 0; j < 8; ++j) {
                float4 q = sm[t0 + j];
                float t = fmaf(px, q.x, q.w);
                t = fmaf(py, q.y, t);
                t = fmaf(pz, q.z, t);
                if ((j & 3) == 0)      mn0 = fminf(mn0, t);
                else if ((j & 3) == 1) mn1 = fminf(mn1, t);
                else if ((j & 3) == 2) mn2 = fminf(mn2, t);
                else                   mn3 = fminf(mn3, t);
            }
        }
        __syncthreads();   // LDS write-after-read guard for next tile
    }

    float mn = fminf(fminf(mn0, mn1), fminf(mn2, mn3));
    float s  = valid * (mn + ph);

    // wave-64 shuffle reduction, one atomic per wave
#pragma unroll
    for (int off = 32; off > 0; off >>= 1) s += __shfl_down(s, off, 64);
    if ((threadIdx.x & 63) == 0) {
        atomicAdd(out + b, s * (2.0f / (float)nq));
    }
}

extern "C" void kernel_launch(void* const* d_in, const int* in_sizes, int n_in,
                              void* d_out, int out_size, void* d_ws, size_t ws_size,
                              hipStream_t stream) {
    const float* xyz1 = (const float*)d_in[0];
    const float* xyz2 = (const float*)d_in[1];
    float* out = (float*)d_out;

    const int B = out_size;                 // one scalar per batch
    const int N = in_sizes[0] / (3 * B);
    const int M = in_sizes[1] / (3 * B);

    hipMemsetAsync(d_out, 0, (size_t)B * sizeof(float), stream);

    const int qmax = N > M ? N : M;
    dim3 grid((qmax + TPB - 1) / TPB, B, 2);
    chamfer_main<<<grid, dim3(TPB), 0, stream>>>(xyz1, xyz2, out, N, M);
}

// Round 3
// 138.254 us; speedup vs baseline: 3.1987x; 1.4039x over previous
//
#include <hip/hip_runtime.h>
#include <hip/hip_bf16.h>

#define TPB 256      // 4 waves per block
#define RQ  8        // query points per thread (registers)
#define TS  4096     // db points resident in LDS (64 KiB as float4)
#define QTR (TS / 4) // points swept per wave per tile

// One block handles 512 query points (64 lanes x RQ) of one (batch, direction).
// The entire db cloud tile (up to 4096 points) is staged once into LDS as
// (x, y, z, 0.5*||.||^2); wave w sweeps quarter w; partial mins combined via LDS.
// d(p,q) = 2*(ph + (hq - p.q)), ph=0.5||p||^2 -> inner step: 3 fma + 1 min.
__global__ __launch_bounds__(TPB, 2) void chamfer_main(const float* __restrict__ xyz1,
                                                       const float* __restrict__ xyz2,
                                                       float* __restrict__ out,
                                                       int N, int M) {
    const int b   = blockIdx.y;
    const int dir = blockIdx.z;
    const float* __restrict__ P = dir ? (xyz2 + (size_t)b * M * 3) : (xyz1 + (size_t)b * N * 3);
    const float* __restrict__ Q = dir ? (xyz1 + (size_t)b * N * 3) : (xyz2 + (size_t)b * M * 3);
    const int nq = dir ? M : N;   // number of query points this direction
    const int md = dir ? N : M;   // number of db points this direction

    __shared__ float4 sm[TS];     // 64 KiB

    const int tid  = (int)threadIdx.x;
    const int w    = tid >> 6;    // wave id 0..3
    const int lane = tid & 63;

    // Load RQ query points (coalesced per wave; all waves load the same 512).
    const int qb = blockIdx.x * (64 * RQ);
    float px[RQ], py[RQ], pz[RQ], ph[RQ], valid[RQ], mn[RQ];
#pragma unroll
    for (int r = 0; r < RQ; ++r) {
        int idx  = qb + lane + 64 * r;
        int cidx = idx < nq ? idx : nq - 1;
        float x = P[3 * cidx + 0];
        float y = P[3 * cidx + 1];
        float z = P[3 * cidx + 2];
        px[r] = -x; py[r] = -y; pz[r] = -z;       // negate once: inner loop is pure fma
        ph[r] = 0.5f * (x * x + y * y + z * z);
        valid[r] = (idx < nq) ? 1.0f : 0.0f;
        mn[r] = 3.0e38f;
    }

    for (int tile = 0; tile < md; tile += TS) {
        if (tile > 0) __syncthreads();   // WAR guard before re-staging
        // Stage up to TS db points; pad with clamped duplicates (harmless for min).
        // Lane-consecutive float4 writes -> conflict-free; coalesced global reads.
#pragma unroll
        for (int k = 0; k < TS / TPB; ++k) {
            int j = tid + k * TPB;
            int g = tile + j;
            g = g < md ? g : md - 1;
            float x = Q[3 * g + 0];
            float y = Q[3 * g + 1];
            float z = Q[3 * g + 2];
            sm[j] = make_float4(x, y, z, 0.5f * (x * x + y * y + z * z));
        }
        __syncthreads();

        // Sweep this wave's quarter: wave-uniform broadcast reads, no barriers.
        const int qoff = w * QTR;
#pragma unroll 4
        for (int t = 0; t < QTR; ++t) {
            float4 q = sm[qoff + t];
#pragma unroll
            for (int r = 0; r < RQ; ++r) {
                float d = fmaf(px[r], q.x, q.w);
                d = fmaf(py[r], q.y, d);
                d = fmaf(pz[r], q.z, d);
                mn[r] = fminf(mn[r], d);
            }
        }
    }

    // Combine the 4 waves' partial mins (each covers a different db quarter).
    __syncthreads();                      // all reads of sm done before reuse
    float* red = (float*)sm;              // 4 * 512 floats = 8 KiB
#pragma unroll
    for (int r = 0; r < RQ; ++r) red[w * (64 * RQ) + lane * RQ + r] = mn[r];
    __syncthreads();

    if (w == 0) {
        float s = 0.0f;
#pragma unroll
        for (int r = 0; r < RQ; ++r) {
            float m0 = red[0 * (64 * RQ) + lane * RQ + r];
            float m1 = red[1 * (64 * RQ) + lane * RQ + r];
            float m2 = red[2 * (64 * RQ) + lane * RQ + r];
            float m3 = red[3 * (64 * RQ) + lane * RQ + r];
            float m  = fminf(fminf(m0, m1), fminf(m2, m3));
            s += valid[r] * (m + ph[r]);
        }
        // wave-64 shuffle reduction, one atomic per block
#pragma unroll
        for (int off = 32; off > 0; off >>= 1) s += __shfl_down(s, off, 64);
        if (lane == 0) atomicAdd(out + b, s * (2.0f / (float)nq));
    }
}

extern "C" void kernel_launch(void* const* d_in, const int* in_sizes, int n_in,
                              void* d_out, int out_size, void* d_ws, size_t ws_size,
                              hipStream_t stream) {
    const float* xyz1 = (const float*)d_in[0];
    const float* xyz2 = (const float*)d_in[1];
    float* out = (float*)d_out;

    const int B = out_size;                 // one scalar per batch
    const int N = in_sizes[0] / (3 * B);
    const int M = in_sizes[1] / (3 * B);

    hipMemsetAsync(d_out, 0, (size_t)B * sizeof(float), stream);

    const int qmax = N > M ? N : M;
    dim3 grid((qmax + 64 * RQ - 1) / (64 * RQ), B, 2);
    chamfer_main<<<grid, dim3(TPB), 0, stream>>>(xyz1, xyz2, out, N, M);
}

// Round 4
// 117.208 us; speedup vs baseline: 3.7731x; 1.1796x over previous
//
#include <hip/hip_runtime.h>
#include <hip/hip_bf16.h>

typedef _Float16 half8 __attribute__((ext_vector_type(8)));
typedef float floatx4 __attribute__((ext_vector_type(4)));

#define TPB   256            // 4 waves
#define RPTS  1024           // db points staged per round
#define NT    (RPTS / 16)    // 64 B-tiles per round
#define SMH   (NT * 256)     // 16384 halfs = 32 KiB staged region

// Each wave owns 64 queries (4 A-frags x 16 rows); block = 256 queries.
// db cloud staged in rounds of 1024 points, pre-formatted as MFMA B-fragments:
//   K-slots k0..k10 = (xh, xl, xh, yh, yl, yh, zh, zl | zh, hqh, hql), rest 0.
// A-slots            = (-xh,-xh,-xl,-yh,-yh,-yl,-zh,-zh | -zl, 1, 1, 0..)
// => acc = 0.5||q||^2 - p.q  (split-f16 exact to ~5e-5);  d = 2*(ph + acc).
// Per lane: rm[16] running col-min; epilogue: 4-step xor-shuffle min over the
// 16-lane quad group, 16 emit lanes add ph, wave shuffle-sum, 1 atomic/wave.
__global__ __launch_bounds__(TPB, 4) void chamfer_mfma(const float* __restrict__ xyz1,
                                                       const float* __restrict__ xyz2,
                                                       float* __restrict__ out,
                                                       int N, int M) {
    const int b = blockIdx.y, dir = blockIdx.z;
    const float* __restrict__ P = dir ? xyz2 + (size_t)b * M * 3 : xyz1 + (size_t)b * N * 3;
    const float* __restrict__ Q = dir ? xyz1 + (size_t)b * N * 3 : xyz2 + (size_t)b * M * 3;
    const int nq = dir ? M : N;
    const int md = dir ? N : M;

    __shared__ __align__(16) _Float16 smB[SMH + 8];   // +8: shared zero chunk

    const int tid  = (int)threadIdx.x;
    const int w    = tid >> 6;
    const int l    = tid & 63;
    const int m    = l & 15;      // A row / B col this lane serves
    const int quad = l >> 4;      // k-slice: k = quad*8 + j

    const _Float16 hz  = (_Float16)0.0f;
    const _Float16 hone = (_Float16)1.0f;

    // ---- Build the wave's 4 A-fragments (held for the whole kernel) ----
    half8 afr[4];
    float ph[4], valid[4];
    const int qb = blockIdx.x * 256 + w * 64;
#pragma unroll
    for (int g = 0; g < 4; ++g) {
        int idx = qb + g * 16 + m;
        int ci  = idx < nq ? idx : nq - 1;
        float x = P[3 * ci], y = P[3 * ci + 1], z = P[3 * ci + 2];
        ph[g]    = 0.5f * (x * x + y * y + z * z);
        valid[g] = idx < nq ? 1.0f : 0.0f;
        _Float16 xh = (_Float16)x, yh = (_Float16)y, zh = (_Float16)z;
        _Float16 xl = (_Float16)(x - (float)xh);
        _Float16 yl = (_Float16)(y - (float)yh);
        _Float16 zl = (_Float16)(z - (float)zh);
        half8 a;
        if (quad == 0) {
            a[0] = -xh; a[1] = -xh; a[2] = -xl; a[3] = -yh;
            a[4] = -yh; a[5] = -yl; a[6] = -zh; a[7] = -zh;
        } else if (quad == 1) {
            a[0] = -zl; a[1] = hone; a[2] = hone; a[3] = hz;
            a[4] = hz;  a[5] = hz;  a[6] = hz;  a[7] = hz;
        } else {
            a[0] = hz; a[1] = hz; a[2] = hz; a[3] = hz;
            a[4] = hz; a[5] = hz; a[6] = hz; a[7] = hz;
        }
        afr[g] = a;
    }

    float rm[16];
#pragma unroll
    for (int i = 0; i < 16; ++i) rm[i] = 3.0e38f;

    const floatx4 czero = {0.0f, 0.0f, 0.0f, 0.0f};
    const int nrounds = (md + RPTS - 1) / RPTS;

    for (int r = 0; r < nrounds; ++r) {
        if (r) __syncthreads();   // WAR guard before restaging
        // ---- Stage 1024 db points as pre-formatted B-fragments ----
#pragma unroll
        for (int k = 0; k < RPTS / TPB; ++k) {
            int j = tid + k * TPB;
            int g = r * RPTS + j;
            g = g < md ? g : md - 1;              // clamp-pad: dups never change a min
            float x = Q[3 * g], y = Q[3 * g + 1], z = Q[3 * g + 2];
            float hq = 0.5f * (x * x + y * y + z * z);
            _Float16 xh = (_Float16)x, yh = (_Float16)y, zh = (_Float16)z;
            _Float16 xl = (_Float16)(x - (float)xh);
            _Float16 yl = (_Float16)(y - (float)yh);
            _Float16 zl = (_Float16)(z - (float)zh);
            _Float16 qh = (_Float16)hq;
            _Float16 ql = (_Float16)(hq - (float)qh);
            int t = j >> 4, c = j & 15;
            half8 v0, v1;
            v0[0] = xh; v0[1] = xl; v0[2] = xh; v0[3] = yh;
            v0[4] = yl; v0[5] = yh; v0[6] = zh; v0[7] = zl;
            v1[0] = zh; v1[1] = qh; v1[2] = ql; v1[3] = hz;
            v1[4] = hz; v1[5] = hz; v1[6] = hz; v1[7] = hz;
            *(half8*)&smB[t * 256 + c * 8]       = v0;   // quad-0 k-slice
            *(half8*)&smB[t * 256 + 128 + c * 8] = v1;   // quad-1 k-slice
        }
        if (r == 0 && tid < 8) smB[SMH + tid] = hz;      // zero chunk (quads 2,3)
        __syncthreads();

        // ---- Sweep: 64 tiles, 2 at a time ----
        const _Float16* bp  = (quad < 2) ? (smB + quad * 128 + m * 8) : (smB + SMH);
        const int       bst = (quad < 2) ? 256 : 0;
        for (int t = 0; t < NT; t += 2) {
            half8 b0 = *(const half8*)bp; bp += bst;
            half8 b1 = *(const half8*)bp; bp += bst;
            floatx4 dA0 = __builtin_amdgcn_mfma_f32_16x16x32_f16(afr[0], b0, czero, 0, 0, 0);
            floatx4 dA1 = __builtin_amdgcn_mfma_f32_16x16x32_f16(afr[1], b0, czero, 0, 0, 0);
            floatx4 dA2 = __builtin_amdgcn_mfma_f32_16x16x32_f16(afr[2], b0, czero, 0, 0, 0);
            floatx4 dA3 = __builtin_amdgcn_mfma_f32_16x16x32_f16(afr[3], b0, czero, 0, 0, 0);
            floatx4 dB0 = __builtin_amdgcn_mfma_f32_16x16x32_f16(afr[0], b1, czero, 0, 0, 0);
            floatx4 dB1 = __builtin_amdgcn_mfma_f32_16x16x32_f16(afr[1], b1, czero, 0, 0, 0);
            floatx4 dB2 = __builtin_amdgcn_mfma_f32_16x16x32_f16(afr[2], b1, czero, 0, 0, 0);
            floatx4 dB3 = __builtin_amdgcn_mfma_f32_16x16x32_f16(afr[3], b1, czero, 0, 0, 0);
#pragma unroll
            for (int i = 0; i < 4; ++i) {
                rm[0 * 4 + i] = fminf(fminf(rm[0 * 4 + i], dA0[i]), dB0[i]);  // -> v_min3
                rm[1 * 4 + i] = fminf(fminf(rm[1 * 4 + i], dA1[i]), dB1[i]);
                rm[2 * 4 + i] = fminf(fminf(rm[2 * 4 + i], dA2[i]), dB2[i]);
                rm[3 * 4 + i] = fminf(fminf(rm[3 * 4 + i], dA3[i]), dB3[i]);
            }
        }
    }

    // ---- Cross-lane col-min within each 16-lane quad group ----
#pragma unroll
    for (int off = 1; off < 16; off <<= 1) {
#pragma unroll
        for (int i = 0; i < 16; ++i) rm[i] = fminf(rm[i], __shfl_xor(rm[i], off, 64));
    }

    // Emit lanes: quad == (l&15)>>2  -> lane owns query row fr = l&15 = 4*quad + (l&3)
    float s = 0.0f;
    if (quad == (m >> 2)) {
        int reg = l & 3;
#pragma unroll
        for (int g = 0; g < 4; ++g) s += valid[g] * (rm[g * 4 + reg] + ph[g]);
    }
    // wave sum + one atomic per wave;  dist = 2*(ph+acc), mean over nq
#pragma unroll
    for (int off = 32; off > 0; off >>= 1) s += __shfl_down(s, off, 64);
    if (l == 0) atomicAdd(out + b, s * (2.0f / (float)nq));
}

extern "C" void kernel_launch(void* const* d_in, const int* in_sizes, int n_in,
                              void* d_out, int out_size, void* d_ws, size_t ws_size,
                              hipStream_t stream) {
    const float* xyz1 = (const float*)d_in[0];
    const float* xyz2 = (const float*)d_in[1];
    float* out = (float*)d_out;

    const int B = out_size;
    const int N = in_sizes[0] / (3 * B);
    const int M = in_sizes[1] / (3 * B);

    hipMemsetAsync(d_out, 0, (size_t)B * sizeof(float), stream);

    const int qmax = N > M ? N : M;
    dim3 grid((qmax + 255) / 256, B, 2);
    chamfer_mfma<<<grid, dim3(TPB), 0, stream>>>(xyz1, xyz2, out, N, M);
}

// Round 5
// 116.449 us; speedup vs baseline: 3.7977x; 1.0065x over previous
//
#include <hip/hip_runtime.h>

typedef _Float16 half8 __attribute__((ext_vector_type(8)));
typedef float floatx16 __attribute__((ext_vector_type(16)));

#define TPB   256            // 4 waves
#define RPTS  1024           // db points staged per round
#define NTILE (RPTS / 32)    // 32 tiles of 32 db points
#define SMH   (RPTS * 16)    // 16384 halfs = 32 KiB

// 32x32x16 f16 MFMA formulation. Each wave owns 64 queries (2 A-frags x 32 rows);
// block = 256 queries. db staged in rounds of 1024 points as pre-formatted
// B-fragments. K-slots (11 of 16 used):
//   B: (xh, xl, xh, yh, yl, yh, zh, zl | zh, hqh, hql, 0..)
//   A: (-xh,-xh,-xl,-yh,-yh,-yl,-zh,-zh | -zl, 1, 1, 0..)
// => acc = 0.5||q||^2 - p.q (split-f16, abs err ~5e-5);  dist = 2*(ph + min acc).
// A layout: row m = lane&31, k = (lane>>5)*8 + j.  B: col c = lane&31, same k.
// C/D: col = lane&31, row = (reg&3) + 8*(reg>>2) + 4*(lane>>5).
__global__ __launch_bounds__(TPB, 4) void chamfer_mfma(const float* __restrict__ xyz1,
                                                       const float* __restrict__ xyz2,
                                                       float* __restrict__ out,
                                                       int N, int M) {
    const int b = blockIdx.y, dir = blockIdx.z;
    const float* __restrict__ P = dir ? xyz2 + (size_t)b * M * 3 : xyz1 + (size_t)b * N * 3;
    const float* __restrict__ Q = dir ? xyz1 + (size_t)b * N * 3 : xyz2 + (size_t)b * M * 3;
    const int nq = dir ? M : N;
    const int md = dir ? N : M;

    if ((int)blockIdx.x * TPB >= nq) return;   // block-uniform, before any barrier

    __shared__ __align__(16) _Float16 smB[SMH];

    const int tid = (int)threadIdx.x;
    const int w   = tid >> 6;
    const int l   = tid & 63;
    const int m   = l & 31;      // A row / B col this lane serves
    const int h   = l >> 5;      // k-half: k = h*8 + j

    const _Float16 hz = (_Float16)0.0f, hone = (_Float16)1.0f;
    const int qb = blockIdx.x * 256 + w * 64;

    // ---- Build the wave's 2 A-fragments (held for the whole kernel) ----
    half8 afr[2];
#pragma unroll
    for (int g = 0; g < 2; ++g) {
        int idx = qb + g * 32 + m;
        int ci  = idx < nq ? idx : nq - 1;
        float x = P[3 * ci], y = P[3 * ci + 1], z = P[3 * ci + 2];
        _Float16 xh = (_Float16)x, yh = (_Float16)y, zh = (_Float16)z;
        _Float16 xl = (_Float16)(x - (float)xh);
        _Float16 yl = (_Float16)(y - (float)yh);
        _Float16 zl = (_Float16)(z - (float)zh);
        half8 a;
        if (h == 0) {
            a[0] = -xh; a[1] = -xh; a[2] = -xl; a[3] = -yh;
            a[4] = -yh; a[5] = -yl; a[6] = -zh; a[7] = -zh;
        } else {
            a[0] = -zl; a[1] = hone; a[2] = hone; a[3] = hz;
            a[4] = hz;  a[5] = hz;   a[6] = hz;  a[7] = hz;
        }
        afr[g] = a;
    }

    float rm[32];
#pragma unroll
    for (int i = 0; i < 32; ++i) rm[i] = 3.0e38f;

    const floatx16 czero = {0.0f, 0.0f, 0.0f, 0.0f, 0.0f, 0.0f, 0.0f, 0.0f,
                            0.0f, 0.0f, 0.0f, 0.0f, 0.0f, 0.0f, 0.0f, 0.0f};
    const int nrounds = (md + RPTS - 1) / RPTS;
    const _Float16* bp = smB + h * 256 + m * 8;

    for (int r = 0; r < nrounds; ++r) {
        if (r) __syncthreads();   // WAR guard before restaging
        // ---- Stage 1024 db points as pre-formatted B-fragments ----
#pragma unroll
        for (int k = 0; k < RPTS / TPB; ++k) {
            int j = tid + k * TPB;
            int g = r * RPTS + j;
            g = g < md ? g : md - 1;              // clamp-pad: dups never change a min
            float x = Q[3 * g], y = Q[3 * g + 1], z = Q[3 * g + 2];
            float hq = 0.5f * (x * x + y * y + z * z);
            _Float16 xh = (_Float16)x, yh = (_Float16)y, zh = (_Float16)z;
            _Float16 xl = (_Float16)(x - (float)xh);
            _Float16 yl = (_Float16)(y - (float)yh);
            _Float16 zl = (_Float16)(z - (float)zh);
            _Float16 qh = (_Float16)hq;
            _Float16 ql = (_Float16)(hq - (float)qh);
            int t = j >> 5, c = j & 31;
            half8 v0, v1;
            v0[0] = xh; v0[1] = xl; v0[2] = xh; v0[3] = yh;
            v0[4] = yl; v0[5] = yh; v0[6] = zh; v0[7] = zl;
            v1[0] = zh; v1[1] = qh; v1[2] = ql; v1[3] = hz;
            v1[4] = hz; v1[5] = hz; v1[6] = hz; v1[7] = hz;
            *(half8*)&smB[t * 512 + c * 8]       = v0;   // k-half 0
            *(half8*)&smB[t * 512 + 256 + c * 8] = v1;   // k-half 1
        }
        __syncthreads();

        // ---- Sweep: 32 tiles, 2 per iteration; min3 fold ----
        for (int t = 0; t < NTILE; t += 2) {
            half8 b0 = *(const half8*)(bp + t * 512);
            half8 b1 = *(const half8*)(bp + t * 512 + 512);
            floatx16 d0a = __builtin_amdgcn_mfma_f32_32x32x16_f16(afr[0], b0, czero, 0, 0, 0);
            floatx16 d0b = __builtin_amdgcn_mfma_f32_32x32x16_f16(afr[0], b1, czero, 0, 0, 0);
#pragma unroll
            for (int i = 0; i < 16; ++i)
                rm[i] = fminf(fminf(rm[i], d0a[i]), d0b[i]);         // -> v_min3
            floatx16 d1a = __builtin_amdgcn_mfma_f32_32x32x16_f16(afr[1], b0, czero, 0, 0, 0);
            floatx16 d1b = __builtin_amdgcn_mfma_f32_32x32x16_f16(afr[1], b1, czero, 0, 0, 0);
#pragma unroll
            for (int i = 0; i < 16; ++i)
                rm[16 + i] = fminf(fminf(rm[16 + i], d1a[i]), d1b[i]);
        }
    }

    // ---- Col-min across the 32 lanes of each k-half (rows identical per half) ----
#pragma unroll
    for (int off = 1; off < 32; off <<= 1) {
#pragma unroll
        for (int i = 0; i < 32; ++i) rm[i] = fminf(rm[i], __shfl_xor(rm[i], off, 64));
    }

    // ---- Emit: lanes c<16 of each half own one row each; recompute ph from P ----
    float s = 0.0f;
    if (m < 16) {
        const int reg = (m & 3) + 4 * (m >> 2);
        const int row = 4 * h + (m & 3) + 8 * (m >> 2);
#pragma unroll
        for (int g = 0; g < 2; ++g) {
            int idx = qb + g * 32 + row;
            if (idx < nq) {
                float x = P[3 * idx], y = P[3 * idx + 1], z = P[3 * idx + 2];
                s += rm[g * 16 + reg] + 0.5f * (x * x + y * y + z * z);
            }
        }
    }
#pragma unroll
    for (int off = 32; off > 0; off >>= 1) s += __shfl_down(s, off, 64);
    if (l == 0) atomicAdd(out + b, s * (2.0f / (float)nq));   // dist = 2*(ph+acc)
}

extern "C" void kernel_launch(void* const* d_in, const int* in_sizes, int n_in,
                              void* d_out, int out_size, void* d_ws, size_t ws_size,
                              hipStream_t stream) {
    const float* xyz1 = (const float*)d_in[0];
    const float* xyz2 = (const float*)d_in[1];
    float* out = (float*)d_out;

    const int B = out_size;
    const int N = in_sizes[0] / (3 * B);
    const int M = in_sizes[1] / (3 * B);

    hipMemsetAsync(d_out, 0, (size_t)B * sizeof(float), stream);

    const int qmax = N > M ? N : M;
    dim3 grid((qmax + 255) / 256, B, 2);
    chamfer_mfma<<<grid, dim3(TPB), 0, stream>>>(xyz1, xyz2, out, N, M);
}